// Round 4
// baseline (292.509 us; speedup 1.0000x reference)
//
#include <hip/hip_runtime.h>
#include <math.h>

#define HDIM 4096
#define NEXP 64
#define NTOK 8192
#define KSPLIT 16
#define KSLICE (HDIM / KSPLIT)   // 256
#define BM 128
#define CHUNK 32
#define NCHUNK (KSLICE / CHUNK)  // 8
#define PSTRIDE 2048             // shorts: one (chunk,part) plane = 64 experts * 32 k
#define CSTRIDE 6144             // shorts: 3 parts per chunk
#define AUXF 1152                // floats: auxbuf 1024 | counter @1024 | pad
#define BSF 393216               // floats holding 786432 shorts of pre-split B (3*64*4096)
#define SLICEOFF (AUXF + BSF)    // slices start here (floats)
#define TPW 2
#define TOPK_BLOCKS (NTOK / (4 * TPW))  // 1024

typedef short short8 __attribute__((ext_vector_type(8)));
typedef float f32x4 __attribute__((ext_vector_type(4)));
typedef const __attribute__((address_space(1))) unsigned int* gas_t;
typedef __attribute__((address_space(3))) unsigned int* las_t;

// Exact 3-way bf16 split of two fp32 values, packed as (lo16=x0, hi16=x1).
// x = hi + mid + lo exactly (8+8+8 mantissa bits covers fp32's 24).
__device__ __forceinline__ void split2x3(float x0, float x1, int& h, int& md, int& lo) {
  unsigned u0 = __float_as_uint(x0), u1 = __float_as_uint(x1);
  unsigned h0 = u0 & 0xFFFF0000u, h1 = u1 & 0xFFFF0000u;
  float r0 = x0 - __uint_as_float(h0);
  float r1 = x1 - __uint_as_float(h1);
  unsigned m0 = __float_as_uint(r0) & 0xFFFF0000u;
  unsigned m1 = __float_as_uint(r1) & 0xFFFF0000u;
  float s0 = r0 - __uint_as_float(m0);
  float s1 = r1 - __uint_as_float(m1);
  h  = (int)((h0 >> 16) | h1);
  md = (int)((m0 >> 16) | m1);
  lo = (int)((__float_as_uint(s0) >> 16) | (__float_as_uint(s1) & 0xFFFF0000u));
}

__device__ __forceinline__ short8 pack_s8(int a, int b, int c, int d) {
  union { int i[4]; short8 s; } u;
  u.i[0] = a; u.i[1] = b; u.i[2] = c; u.i[3] = d;
  return u.s;
}

// ---------------------------------------------------------------------------
// Pre-split gate_w into bf16x3 planes, layout [chunk c][part][expert][32 k].
// 1.5 MB -> L2-resident. Block 0 additionally zeroes auxbuf + semaphore
// (replaces the separate hipMemsetAsync dispatch: one fewer launch gap).
// ---------------------------------------------------------------------------
__global__ void bsplit_k(const float* __restrict__ W, short* __restrict__ Bs,
                         float* __restrict__ wsbase) {
  const int e = blockIdx.x;      // 64 experts
  const int tid = threadIdx.x;   // 256
  if (e == 0) {
#pragma unroll
    for (int t = tid; t < AUXF; t += 256) wsbase[t] = 0.f;
  }
#pragma unroll
  for (int it = 0; it < 2; ++it) {
    const int k0 = tid * 16 + it * 8;  // 0..4088
    const float4 v0 = *(const float4*)&W[(size_t)e * HDIM + k0];
    const float4 v1 = *(const float4*)&W[(size_t)e * HDIM + k0 + 4];
    const float f[8] = {v0.x, v0.y, v0.z, v0.w, v1.x, v1.y, v1.z, v1.w};
    int h[4], md[4], lo[4];
#pragma unroll
    for (int j = 0; j < 4; ++j) split2x3(f[2 * j], f[2 * j + 1], h[j], md[j], lo[j]);
    const int c = k0 >> 5, kk = k0 & 31;
    short* p = Bs + (size_t)c * CSTRIDE + (size_t)e * 32 + kk;
    *(int4*)(p)               = make_int4(h[0], h[1], h[2], h[3]);
    *(int4*)(p + PSTRIDE)     = make_int4(md[0], md[1], md[2], md[3]);
    *(int4*)(p + 2 * PSTRIDE) = make_int4(lo[0], lo[1], lo[2], lo[3]);
  }
}

// ---------------------------------------------------------------------------
// GEMM v4: counted-vmcnt pipeline (T3/T4-lite). Per chunk:
//   loadB(i) [12 dwordx4] -> s_waitcnt vmcnt(12) -> raw s_barrier
//   -> stageA(i+1) DMA -> ds_read+split -> 48 MFMA.
// Sync ledger (2 LDS buffers):
//  * vmcnt(12) drains exactly this wave's stageA(i) (issued post-barrier at
//    iter i-1; the 12 B(i) loads are newer) BEFORE the barrier -> after the
//    barrier ALL waves' As[i] DMA is complete -> reads safe.
//  * B(i)'s 12 loads stay in flight across the barrier; the compiler's own
//    dataflow wait (vmcnt(4): only stageA(i+1) newer) drains them right
//    before the MFMAs -> barrier no longer serializes the A-DMA latency.
//  * stageA(i+1) writes buf (i+1)&1, last read at chunk i-1; all those reads
//    completed before barrier(i) (each wave finishes compute(i-1), then
//    loadB/vmcnt, then arrives) -> no write/read race.
// Numerics identical to the round-0 passing kernel.
// ---------------------------------------------------------------------------
__global__ __launch_bounds__(256, 4) void gemm_k(const float* __restrict__ A,
                                                 const short* __restrict__ Bs,
                                                 float* __restrict__ Lp,
                                                 int atomic_mode) {
  __shared__ __align__(16) float As[2][BM * CHUNK];  // 2 x 16 KB
  const int tid = threadIdx.x;
  const int m_base = blockIdx.x * BM;
  const int k_base = blockIdx.y * KSLICE;
  float* Lout = Lp + (atomic_mode ? (size_t)0 : (size_t)blockIdx.y * NTOK * NEXP);

  const int lane = tid & 63;
  const int wave = tid >> 6;
  const int l15 = lane & 15;
  const int quad = lane >> 4;
  const int wm = wave * 32;

  // --- A staging geometry (global_load_lds: lane l -> ldsbase + l*16B) ---
  // slot S=(wave*4+j)*64+lane holds row = S>>3, swizzled colblk sw = S&7;
  // global colblk c = sw ^ (row&7) = (lane&7) ^ (lane>>3)
  const int rowp = wave * 32 + (lane >> 3);
  const int cblk = (lane & 7) ^ (lane >> 3);
  const float* gA0 = A + (size_t)(m_base + rowp) * HDIM + k_base + cblk * 4;

  auto stageA = [&](int i, int buf) {
#pragma unroll
    for (int j = 0; j < 4; ++j) {
      const float* src = gA0 + (size_t)(j * 8) * HDIM + i * CHUNK;
      __builtin_amdgcn_global_load_lds((gas_t)(const void*)src,
                                       (las_t)(void*)&As[buf][(wave * 4 + j) * 256],
                                       16, 0, 0);
    }
  };

  // --- B fragments: [chunk][part][expert=nt*16+l15][quad*8..] from L2 ---
  const short* bbase = Bs + (size_t)(k_base >> 5) * CSTRIDE + (size_t)l15 * 32 + quad * 8;
  short8 breg[12];
  auto loadB = [&](int i) {
    const short* bp = bbase + (size_t)i * CSTRIDE;
#pragma unroll
    for (int nt = 0; nt < 4; ++nt)
#pragma unroll
      for (int p = 0; p < 3; ++p)
        breg[nt * 3 + p] = *(const short8*)(bp + nt * 512 + p * PSTRIDE);
  };

  f32x4 acc[2][4];
#pragma unroll
  for (int mt = 0; mt < 2; ++mt)
#pragma unroll
    for (int nt = 0; nt < 4; ++nt) acc[mt][nt] = (f32x4){0.f, 0.f, 0.f, 0.f};

  stageA(0, 0);  // 4 loads in flight; drained by iter-0's vmcnt(12) (4+12=16 -> 12)

  for (int i = 0; i < NCHUNK; ++i) {
    const int buf = i & 1;
    loadB(i);  // 12 loads, newest; left in flight across the barrier
    asm volatile("s_waitcnt vmcnt(12)" ::: "memory");  // drain own stageA(i)
    __builtin_amdgcn_s_barrier();
    asm volatile("" ::: "memory");  // no LDS access crosses the barrier
    if (i + 1 < NCHUNK) stageA(i + 1, buf ^ 1);  // full iteration of flight

#pragma unroll
    for (int mt = 0; mt < 2; ++mt) {
      const int r = wm + mt * 16 + l15;
      const int rb = r * CHUNK;
      const int sw = r & 7;
      const float4 a0 = *(const float4*)&As[buf][rb + ((2 * quad) ^ sw) * 4];
      const float4 a1 = *(const float4*)&As[buf][rb + ((2 * quad + 1) ^ sw) * 4];
      const float f[8] = {a0.x, a0.y, a0.z, a0.w, a1.x, a1.y, a1.z, a1.w};
      int h[4], md[4], lo[4];
#pragma unroll
      for (int j = 0; j < 4; ++j) split2x3(f[2 * j], f[2 * j + 1], h[j], md[j], lo[j]);
      const short8 fh = pack_s8(h[0], h[1], h[2], h[3]);
      const short8 fm = pack_s8(md[0], md[1], md[2], md[3]);
      const short8 fl = pack_s8(lo[0], lo[1], lo[2], lo[3]);
#pragma unroll
      for (int nt = 0; nt < 4; ++nt) {
        const short8 bh = breg[nt * 3 + 0];
        const short8 bm = breg[nt * 3 + 1];
        const short8 bl = breg[nt * 3 + 2];
        f32x4 c = acc[mt][nt];
        c = __builtin_amdgcn_mfma_f32_16x16x32_bf16(fh, bh, c, 0, 0, 0);
        c = __builtin_amdgcn_mfma_f32_16x16x32_bf16(fh, bm, c, 0, 0, 0);
        c = __builtin_amdgcn_mfma_f32_16x16x32_bf16(fm, bh, c, 0, 0, 0);
        c = __builtin_amdgcn_mfma_f32_16x16x32_bf16(fh, bl, c, 0, 0, 0);
        c = __builtin_amdgcn_mfma_f32_16x16x32_bf16(fl, bh, c, 0, 0, 0);
        c = __builtin_amdgcn_mfma_f32_16x16x32_bf16(fm, bm, c, 0, 0, 0);
        acc[mt][nt] = c;
      }
    }
  }

#pragma unroll
  for (int mt = 0; mt < 2; ++mt)
#pragma unroll
    for (int nt = 0; nt < 4; ++nt)
#pragma unroll
      for (int r = 0; r < 4; ++r) {
        const int m = m_base + wm + mt * 16 + quad * 4 + r;
        const int n = nt * 16 + l15;
        if (atomic_mode) atomicAdd(&Lout[(size_t)m * NEXP + n], acc[mt][nt][r]);
        else Lout[(size_t)m * NEXP + n] = acc[mt][nt][r];
      }
}

// ---------------------------------------------------------------------------
// Top-k router, wave-per-token (lane = expert), unrolled 16-slice reduction.
// Fused aux epilogue: split-K semaphore — last block to finish reads auxbuf
// (agent-scope loads; atomics from other XCDs visible at the coherent point)
// and writes the aux loss. Removes the aux_k launch (+gap).
// ---------------------------------------------------------------------------
__global__ __launch_bounds__(256) void topk_k(const float* __restrict__ Lp, int nsl,
                                              float* __restrict__ out,
                                              float* __restrict__ auxbuf,
                                              unsigned* __restrict__ counter) {
  __shared__ float sl[4][64];
  __shared__ float s_aux[128];  // [0:64) prob sums, [64:128) pick counts
  __shared__ int slast;
  const int tid = threadIdx.x;
  const int wave = tid >> 6, lane = tid & 63;
  if (tid < 128) s_aux[tid] = 0.f;
  __syncthreads();

  for (int it = 0; it < TPW; ++it) {
    const int t = (blockIdx.x * 4 + wave) * TPW + it;
    float x = 0.f;
    if (nsl == KSPLIT) {
#pragma unroll
      for (int s = 0; s < KSPLIT; ++s)
        x += Lp[(size_t)s * (NTOK * NEXP) + (size_t)t * NEXP + lane];
    } else {
      for (int s = 0; s < nsl; ++s)
        x += Lp[(size_t)s * (NTOK * NEXP) + (size_t)t * NEXP + lane];
    }
    sl[wave][lane] = x;

    float mx = x;
#pragma unroll
    for (int off = 32; off >= 1; off >>= 1)
      mx = fmaxf(mx, __shfl_xor(mx, off, 64));
    const float e = __expf(x - mx);
    float ssum = e;
#pragma unroll
    for (int off = 32; off >= 1; off >>= 1) ssum += __shfl_xor(ssum, off, 64);
    const float prob = e / ssum;

    __syncthreads();  // sl visible (uniform barrier: same trip count all waves)

    int cnt = 0;
#pragma unroll
    for (int c = 0; c < 4; ++c) {
      const float4 v0 = *(const float4*)&sl[wave][c * 16 + 0];
      const float4 v1 = *(const float4*)&sl[wave][c * 16 + 4];
      const float4 v2 = *(const float4*)&sl[wave][c * 16 + 8];
      const float4 v3 = *(const float4*)&sl[wave][c * 16 + 12];
      const float xv[16] = {v0.x, v0.y, v0.z, v0.w, v1.x, v1.y, v1.z, v1.w,
                            v2.x, v2.y, v2.z, v2.w, v3.x, v3.y, v3.z, v3.w};
#pragma unroll
      for (int j = 0; j < 16; ++j) {
        const int jj = c * 16 + j;
        cnt += (xv[j] > x) || (xv[j] == x && jj < lane);
      }
    }

    float tp = (cnt < 8) ? prob : 0.f;
    float tsum = tp;
#pragma unroll
    for (int off = 32; off >= 1; off >>= 1) tsum += __shfl_xor(tsum, off, 64);

    const int dst = cnt << 2;  // ranks are a permutation -> collision-free
    const float pv = __uint_as_float(
        (unsigned)__builtin_amdgcn_ds_permute(dst, (int)__float_as_uint(prob)));
    const int pi = __builtin_amdgcn_ds_permute(dst, lane);
    if (lane < 8) {
      out[(size_t)t * 8 + lane] = pv / tsum;
      out[(size_t)NTOK * 8 + (size_t)t * 8 + lane] = (float)pi;
    }
    atomicAdd(&s_aux[lane], prob);
    if (cnt < 8) atomicAdd(&s_aux[64 + lane], 1.f);
  }
  __syncthreads();
  if (tid < 128) atomicAdd(&auxbuf[(blockIdx.x & 7) * 128 + tid], s_aux[tid]);

  // --- fused aux epilogue (split-K semaphore) ---
  __threadfence();   // release: my auxbuf atomics globally visible ...
  __syncthreads();   // ... for ALL threads of this block, before the counter
  if (tid == 0) {
    unsigned done = __hip_atomic_fetch_add(counter, 1u, __ATOMIC_ACQ_REL,
                                           __HIP_MEMORY_SCOPE_AGENT);
    slast = (done == (unsigned)(gridDim.x - 1)) ? 1 : 0;
  }
  __syncthreads();
  if (slast && tid < 64) {
    float p = 0.f, f = 0.f;
#pragma unroll
    for (int c = 0; c < 8; ++c) {
      p += __hip_atomic_load(&auxbuf[c * 128 + tid], __ATOMIC_RELAXED,
                             __HIP_MEMORY_SCOPE_AGENT);
      f += __hip_atomic_load(&auxbuf[c * 128 + 64 + tid], __ATOMIC_RELAXED,
                             __HIP_MEMORY_SCOPE_AGENT);
    }
    p *= (1.f / (float)NTOK);
    f *= (1.f / ((float)NTOK * 8.f));
    float v = f * p;
#pragma unroll
    for (int off = 32; off >= 1; off >>= 1) v += __shfl_xor(v, off, 64);
    if (tid == 0) out[2 * NTOK * 8] = 64.f * v;
  }
}

extern "C" void kernel_launch(void* const* d_in, const int* in_sizes, int n_in,
                              void* d_out, int out_size, void* d_ws, size_t ws_size,
                              hipStream_t stream) {
  const float* hidden = (const float*)d_in[0];  // 8192 x 4096 fp32
  const float* gate = (const float*)d_in[1];    // 64 x 4096 fp32
  float* out = (float*)d_out;                   // [w 65536 | idx 65536 | aux 1]
  float* ws = (float*)d_ws;
  float* auxbuf = ws;                           // 8 copies x 128 floats
  unsigned* counter = (unsigned*)(ws + 1024);   // topk semaphore
  short* Bs = (short*)(ws + AUXF);              // pre-split B, 1.5 MB
  float* slices = ws + SLICEOFF;                // KSPLIT x (8192*64) fp32 partials

  const size_t need = (size_t)SLICEOFF * 4 + (size_t)KSPLIT * NTOK * NEXP * 4;
  const int atomic_mode = (ws_size < need) ? 1 : 0;
  const int nsl = atomic_mode ? 1 : KSPLIT;

  if (atomic_mode)  // fallback only; zeroes logits accumulator (+aux region)
    hipMemsetAsync(d_ws, 0, (size_t)SLICEOFF * 4 + (size_t)NTOK * NEXP * 4, stream);

  bsplit_k<<<NEXP, 256, 0, stream>>>(gate, Bs, ws);  // also zeroes auxbuf+counter
  gemm_k<<<dim3(64, KSPLIT), 256, 0, stream>>>(hidden, Bs, slices, atomic_mode);
  topk_k<<<TOPK_BLOCKS, 256, 0, stream>>>(slices, nsl, out, auxbuf, counter);
}

// Round 5
// 221.804 us; speedup vs baseline: 1.3188x; 1.3188x over previous
//
#include <hip/hip_runtime.h>
#include <math.h>

#define HDIM 4096
#define NEXP 64
#define NTOK 8192
#define KSPLIT 16
#define KSLICE (HDIM / KSPLIT)   // 256
#define BM 128
#define CHUNK 32
#define NCHUNK (KSLICE / CHUNK)  // 8
#define PSTRIDE 2048             // shorts: one (chunk,part) plane = 64 experts * 32 k
#define CSTRIDE 6144             // shorts: 3 parts per chunk
#define AUXCOPIES 32             // auxbuf spread (32-way contention, was 128-way)
#define AUXF (AUXCOPIES * 128)   // floats of auxbuf
#define BSF 393216               // floats holding 786432 shorts of pre-split B (3*64*4096)
#define SLICEOFF (AUXF + BSF)    // slices start here (floats)
#define TPW 2
#define TOPK_BLOCKS (NTOK / (4 * TPW))  // 1024

typedef short short8 __attribute__((ext_vector_type(8)));
typedef float f32x4 __attribute__((ext_vector_type(4)));
typedef const __attribute__((address_space(1))) unsigned int* gas_t;
typedef __attribute__((address_space(3))) unsigned int* las_t;

// Exact 3-way bf16 split of two fp32 values, packed as (lo16=x0, hi16=x1).
// x = hi + mid + lo exactly (8+8+8 mantissa bits covers fp32's 24).
__device__ __forceinline__ void split2x3(float x0, float x1, int& h, int& md, int& lo) {
  unsigned u0 = __float_as_uint(x0), u1 = __float_as_uint(x1);
  unsigned h0 = u0 & 0xFFFF0000u, h1 = u1 & 0xFFFF0000u;
  float r0 = x0 - __uint_as_float(h0);
  float r1 = x1 - __uint_as_float(h1);
  unsigned m0 = __float_as_uint(r0) & 0xFFFF0000u;
  unsigned m1 = __float_as_uint(r1) & 0xFFFF0000u;
  float s0 = r0 - __uint_as_float(m0);
  float s1 = r1 - __uint_as_float(m1);
  h  = (int)((h0 >> 16) | h1);
  md = (int)((m0 >> 16) | m1);
  lo = (int)((__float_as_uint(s0) >> 16) | (__float_as_uint(s1) & 0xFFFF0000u));
}

__device__ __forceinline__ short8 pack_s8(int a, int b, int c, int d) {
  union { int i[4]; short8 s; } u;
  u.i[0] = a; u.i[1] = b; u.i[2] = c; u.i[3] = d;
  return u.s;
}

// ---------------------------------------------------------------------------
// Pre-split gate_w into bf16x3 planes, layout [chunk c][part][expert][32 k].
// 1.5 MB -> L2-resident. Block 0 additionally zeroes auxbuf (replaces the
// separate hipMemsetAsync dispatch).
// ---------------------------------------------------------------------------
__global__ void bsplit_k(const float* __restrict__ W, short* __restrict__ Bs,
                         float* __restrict__ wsbase) {
  const int e = blockIdx.x;      // 64 experts
  const int tid = threadIdx.x;   // 256
  if (e == 0) {
#pragma unroll
    for (int t = tid; t < AUXF; t += 256) wsbase[t] = 0.f;
  }
#pragma unroll
  for (int it = 0; it < 2; ++it) {
    const int k0 = tid * 16 + it * 8;  // 0..4088
    const float4 v0 = *(const float4*)&W[(size_t)e * HDIM + k0];
    const float4 v1 = *(const float4*)&W[(size_t)e * HDIM + k0 + 4];
    const float f[8] = {v0.x, v0.y, v0.z, v0.w, v1.x, v1.y, v1.z, v1.w};
    int h[4], md[4], lo[4];
#pragma unroll
    for (int j = 0; j < 4; ++j) split2x3(f[2 * j], f[2 * j + 1], h[j], md[j], lo[j]);
    const int c = k0 >> 5, kk = k0 & 31;
    short* p = Bs + (size_t)c * CSTRIDE + (size_t)e * 32 + kk;
    *(int4*)(p)               = make_int4(h[0], h[1], h[2], h[3]);
    *(int4*)(p + PSTRIDE)     = make_int4(md[0], md[1], md[2], md[3]);
    *(int4*)(p + 2 * PSTRIDE) = make_int4(lo[0], lo[1], lo[2], lo[3]);
  }
}

// ---------------------------------------------------------------------------
// GEMM v4 (unchanged from round 4): counted-vmcnt pipeline. Per chunk:
//   loadB(i) [12 dwordx4] -> s_waitcnt vmcnt(12) -> raw s_barrier
//   -> stageA(i+1) DMA -> ds_read+split -> 48 MFMA.
// Sync ledger: vmcnt(12) drains exactly this wave's stageA(i) before the
// barrier (12 newer B loads stay in flight); compiler's dataflow wait drains
// B before the MFMAs; stageA(i+1)'s buffer was last read at chunk i-1.
// ---------------------------------------------------------------------------
__global__ __launch_bounds__(256, 4) void gemm_k(const float* __restrict__ A,
                                                 const short* __restrict__ Bs,
                                                 float* __restrict__ Lp,
                                                 int atomic_mode) {
  __shared__ __align__(16) float As[2][BM * CHUNK];  // 2 x 16 KB
  const int tid = threadIdx.x;
  const int m_base = blockIdx.x * BM;
  const int k_base = blockIdx.y * KSLICE;
  float* Lout = Lp + (atomic_mode ? (size_t)0 : (size_t)blockIdx.y * NTOK * NEXP);

  const int lane = tid & 63;
  const int wave = tid >> 6;
  const int l15 = lane & 15;
  const int quad = lane >> 4;
  const int wm = wave * 32;

  // --- A staging geometry (global_load_lds: lane l -> ldsbase + l*16B) ---
  // slot S=(wave*4+j)*64+lane holds row = S>>3, swizzled colblk sw = S&7;
  // global colblk c = sw ^ (row&7) = (lane&7) ^ (lane>>3)
  const int rowp = wave * 32 + (lane >> 3);
  const int cblk = (lane & 7) ^ (lane >> 3);
  const float* gA0 = A + (size_t)(m_base + rowp) * HDIM + k_base + cblk * 4;

  auto stageA = [&](int i, int buf) {
#pragma unroll
    for (int j = 0; j < 4; ++j) {
      const float* src = gA0 + (size_t)(j * 8) * HDIM + i * CHUNK;
      __builtin_amdgcn_global_load_lds((gas_t)(const void*)src,
                                       (las_t)(void*)&As[buf][(wave * 4 + j) * 256],
                                       16, 0, 0);
    }
  };

  // --- B fragments: [chunk][part][expert=nt*16+l15][quad*8..] from L2 ---
  const short* bbase = Bs + (size_t)(k_base >> 5) * CSTRIDE + (size_t)l15 * 32 + quad * 8;
  short8 breg[12];
  auto loadB = [&](int i) {
    const short* bp = bbase + (size_t)i * CSTRIDE;
#pragma unroll
    for (int nt = 0; nt < 4; ++nt)
#pragma unroll
      for (int p = 0; p < 3; ++p)
        breg[nt * 3 + p] = *(const short8*)(bp + nt * 512 + p * PSTRIDE);
  };

  f32x4 acc[2][4];
#pragma unroll
  for (int mt = 0; mt < 2; ++mt)
#pragma unroll
    for (int nt = 0; nt < 4; ++nt) acc[mt][nt] = (f32x4){0.f, 0.f, 0.f, 0.f};

  stageA(0, 0);  // 4 loads in flight; drained by iter-0's vmcnt(12)

  for (int i = 0; i < NCHUNK; ++i) {
    const int buf = i & 1;
    loadB(i);  // 12 loads, newest; left in flight across the barrier
    asm volatile("s_waitcnt vmcnt(12)" ::: "memory");  // drain own stageA(i)
    __builtin_amdgcn_s_barrier();
    asm volatile("" ::: "memory");
    if (i + 1 < NCHUNK) stageA(i + 1, buf ^ 1);  // full iteration of flight

#pragma unroll
    for (int mt = 0; mt < 2; ++mt) {
      const int r = wm + mt * 16 + l15;
      const int rb = r * CHUNK;
      const int sw = r & 7;
      const float4 a0 = *(const float4*)&As[buf][rb + ((2 * quad) ^ sw) * 4];
      const float4 a1 = *(const float4*)&As[buf][rb + ((2 * quad + 1) ^ sw) * 4];
      const float f[8] = {a0.x, a0.y, a0.z, a0.w, a1.x, a1.y, a1.z, a1.w};
      int h[4], md[4], lo[4];
#pragma unroll
      for (int j = 0; j < 4; ++j) split2x3(f[2 * j], f[2 * j + 1], h[j], md[j], lo[j]);
      const short8 fh = pack_s8(h[0], h[1], h[2], h[3]);
      const short8 fm = pack_s8(md[0], md[1], md[2], md[3]);
      const short8 fl = pack_s8(lo[0], lo[1], lo[2], lo[3]);
#pragma unroll
      for (int nt = 0; nt < 4; ++nt) {
        const short8 bh = breg[nt * 3 + 0];
        const short8 bm = breg[nt * 3 + 1];
        const short8 bl = breg[nt * 3 + 2];
        f32x4 c = acc[mt][nt];
        c = __builtin_amdgcn_mfma_f32_16x16x32_bf16(fh, bh, c, 0, 0, 0);
        c = __builtin_amdgcn_mfma_f32_16x16x32_bf16(fh, bm, c, 0, 0, 0);
        c = __builtin_amdgcn_mfma_f32_16x16x32_bf16(fm, bh, c, 0, 0, 0);
        c = __builtin_amdgcn_mfma_f32_16x16x32_bf16(fh, bl, c, 0, 0, 0);
        c = __builtin_amdgcn_mfma_f32_16x16x32_bf16(fl, bh, c, 0, 0, 0);
        c = __builtin_amdgcn_mfma_f32_16x16x32_bf16(fm, bm, c, 0, 0, 0);
        acc[mt][nt] = c;
      }
    }
  }

#pragma unroll
  for (int mt = 0; mt < 2; ++mt)
#pragma unroll
    for (int nt = 0; nt < 4; ++nt)
#pragma unroll
      for (int r = 0; r < 4; ++r) {
        const int m = m_base + wm + mt * 16 + quad * 4 + r;
        const int n = nt * 16 + l15;
        if (atomic_mode) atomicAdd(&Lout[(size_t)m * NEXP + n], acc[mt][nt][r]);
        else Lout[(size_t)m * NEXP + n] = acc[mt][nt][r];
      }
}

// ---------------------------------------------------------------------------
// Top-k router v3, wave-per-token-pair (lane = expert).
//  - Both tokens' 32 slice loads prefetched to regs upfront (2x MLP; loads
//    overlap token-0 compute instead of 25% load duty cycle)
//  - The two tokens' shuffle-reduce chains interleaved (ILP hides shfl lat)
//  - Single barrier; auxbuf spread widened to 32 copies (atomic contention)
//  - NO device-scope fence/semaphore (round-4 lesson: buffer_wbl2/inv per
//    block wrecked L2 residency; aux stays a separate tiny kernel)
// ---------------------------------------------------------------------------
__global__ __launch_bounds__(256) void topk_k(const float* __restrict__ Lp, int nsl,
                                              float* __restrict__ out,
                                              float* __restrict__ auxbuf) {
  __shared__ float sl[2][4][64];
  __shared__ float s_aux[128];  // [0:64) prob sums, [64:128) pick counts
  const int tid = threadIdx.x;
  const int wave = tid >> 6, lane = tid & 63;
  if (tid < 128) s_aux[tid] = 0.f;

  const int t0 = (blockIdx.x * 4 + wave) * TPW;
  float x0 = 0.f, x1 = 0.f;
  if (nsl == KSPLIT) {
    float v[2][KSPLIT];
#pragma unroll
    for (int tok = 0; tok < 2; ++tok)
#pragma unroll
      for (int s = 0; s < KSPLIT; ++s)
        v[tok][s] = Lp[(size_t)s * (NTOK * NEXP) + (size_t)(t0 + tok) * NEXP + lane];
#pragma unroll
    for (int s = 0; s < KSPLIT; ++s) { x0 += v[0][s]; x1 += v[1][s]; }
  } else {
    for (int s = 0; s < nsl; ++s) {
      x0 += Lp[(size_t)s * (NTOK * NEXP) + (size_t)t0 * NEXP + lane];
      x1 += Lp[(size_t)s * (NTOK * NEXP) + (size_t)(t0 + 1) * NEXP + lane];
    }
  }
  sl[0][wave][lane] = x0;
  sl[1][wave][lane] = x1;

  // interleaved softmax reductions (independent chains)
  float m0 = x0, m1 = x1;
#pragma unroll
  for (int off = 32; off >= 1; off >>= 1) {
    m0 = fmaxf(m0, __shfl_xor(m0, off, 64));
    m1 = fmaxf(m1, __shfl_xor(m1, off, 64));
  }
  const float e0 = __expf(x0 - m0), e1 = __expf(x1 - m1);
  float ss0 = e0, ss1 = e1;
#pragma unroll
  for (int off = 32; off >= 1; off >>= 1) {
    ss0 += __shfl_xor(ss0, off, 64);
    ss1 += __shfl_xor(ss1, off, 64);
  }
  const float p0 = e0 / ss0, p1 = e1 / ss1;

  __syncthreads();  // sl + s_aux-init visible

  // stable ranks (permutation matching lax.top_k order), both tokens
  int c0 = 0, c1 = 0;
#pragma unroll
  for (int c = 0; c < 4; ++c) {
#pragma unroll
    for (int tok = 0; tok < 2; ++tok) {
      const float4 w0 = *(const float4*)&sl[tok][wave][c * 16 + 0];
      const float4 w1 = *(const float4*)&sl[tok][wave][c * 16 + 4];
      const float4 w2 = *(const float4*)&sl[tok][wave][c * 16 + 8];
      const float4 w3 = *(const float4*)&sl[tok][wave][c * 16 + 12];
      const float xv[16] = {w0.x, w0.y, w0.z, w0.w, w1.x, w1.y, w1.z, w1.w,
                            w2.x, w2.y, w2.z, w2.w, w3.x, w3.y, w3.z, w3.w};
      const float xr = tok ? x1 : x0;
      int cc = 0;
#pragma unroll
      for (int j = 0; j < 16; ++j) {
        const int jj = c * 16 + j;
        cc += (xv[j] > xr) || (xv[j] == xr && jj < lane);
      }
      if (tok) c1 += cc; else c0 += cc;
    }
  }

  float tp0 = (c0 < 8) ? p0 : 0.f;
  float tp1 = (c1 < 8) ? p1 : 0.f;
  float ts0 = tp0, ts1 = tp1;
#pragma unroll
  for (int off = 32; off >= 1; off >>= 1) {
    ts0 += __shfl_xor(ts0, off, 64);
    ts1 += __shfl_xor(ts1, off, 64);
  }

  // ranks are a permutation -> collision-free scatter to lanes 0..7
  const float pv0 = __uint_as_float(
      (unsigned)__builtin_amdgcn_ds_permute(c0 << 2, (int)__float_as_uint(p0)));
  const int pi0 = __builtin_amdgcn_ds_permute(c0 << 2, lane);
  const float pv1 = __uint_as_float(
      (unsigned)__builtin_amdgcn_ds_permute(c1 << 2, (int)__float_as_uint(p1)));
  const int pi1 = __builtin_amdgcn_ds_permute(c1 << 2, lane);
  if (lane < 8) {
    out[(size_t)t0 * 8 + lane] = pv0 / ts0;
    out[(size_t)NTOK * 8 + (size_t)t0 * 8 + lane] = (float)pi0;
    out[(size_t)(t0 + 1) * 8 + lane] = pv1 / ts1;
    out[(size_t)NTOK * 8 + (size_t)(t0 + 1) * 8 + lane] = (float)pi1;
  }
  atomicAdd(&s_aux[lane], p0 + p1);
  const float cadd = (c0 < 8 ? 1.f : 0.f) + (c1 < 8 ? 1.f : 0.f);
  atomicAdd(&s_aux[64 + lane], cadd);

  __syncthreads();
  if (tid < 128)
    atomicAdd(&auxbuf[(blockIdx.x & (AUXCOPIES - 1)) * 128 + tid], s_aux[tid]);
}

// aux = E * sum_e (count_e/(T*K)) * (sumprob_e/T), over AUXCOPIES copies
__global__ void aux_k(const float* __restrict__ auxbuf, float* __restrict__ out) {
  const int e = threadIdx.x;  // 64 threads
  float p = 0.f, f = 0.f;
#pragma unroll
  for (int c = 0; c < AUXCOPIES; ++c) {
    p += auxbuf[c * 128 + e];
    f += auxbuf[c * 128 + 64 + e];
  }
  p *= (1.f / (float)NTOK);
  f *= (1.f / ((float)NTOK * 8.f));
  float v = f * p;
#pragma unroll
  for (int off = 32; off >= 1; off >>= 1) v += __shfl_xor(v, off, 64);
  if (e == 0) out[2 * NTOK * 8] = 64.f * v;
}

extern "C" void kernel_launch(void* const* d_in, const int* in_sizes, int n_in,
                              void* d_out, int out_size, void* d_ws, size_t ws_size,
                              hipStream_t stream) {
  const float* hidden = (const float*)d_in[0];  // 8192 x 4096 fp32
  const float* gate = (const float*)d_in[1];    // 64 x 4096 fp32
  float* out = (float*)d_out;                   // [w 65536 | idx 65536 | aux 1]
  float* ws = (float*)d_ws;
  float* auxbuf = ws;                           // AUXCOPIES x 128 floats
  short* Bs = (short*)(ws + AUXF);              // pre-split B, 1.5 MB
  float* slices = ws + SLICEOFF;                // KSPLIT x (8192*64) fp32 partials

  const size_t need = (size_t)SLICEOFF * 4 + (size_t)KSPLIT * NTOK * NEXP * 4;
  const int atomic_mode = (ws_size < need) ? 1 : 0;
  const int nsl = atomic_mode ? 1 : KSPLIT;

  if (atomic_mode)  // fallback only; zeroes aux region + logits accumulator
    hipMemsetAsync(d_ws, 0, (size_t)SLICEOFF * 4 + (size_t)NTOK * NEXP * 4, stream);

  bsplit_k<<<NEXP, 256, 0, stream>>>(gate, Bs, ws);  // also zeroes auxbuf
  gemm_k<<<dim3(64, KSPLIT), 256, 0, stream>>>(hidden, Bs, slices, atomic_mode);
  topk_k<<<TOPK_BLOCKS, 256, 0, stream>>>(slices, nsl, out, auxbuf);
  aux_k<<<1, 64, 0, stream>>>(auxbuf, out);
}